// Round 13
// baseline (270.846 us; speedup 1.0000x reference)
//
#include <hip/hip_runtime.h>

// ---------------------------------------------------------------------------
// CrossModalAttention: out = (attn(v_q, t_k, t_v) + attn(t_q, v_k, v_v)) @ W_out
// Pipeline: k_prep (fp32->bf16 once) -> k_gemm_qkv_b (global_load_lds A) ->
// k_vt (V^T once) -> k_attn splitKV x2 (fixed-max softmax, P in regs,
// ROW-SUMS VIA MFMA vs all-ones B, shared zero C-in, bf16 partials) ->
// k_combine -> k_gemm_out_b.
// MFMA bf16/fp32-acc; A and B fragments always use the SAME k-bijection so
// HW slot->k schedule cancels. C/D: col=lane&15, row=4*(lane>>4)+reg.
// ---------------------------------------------------------------------------

typedef short  frag8 __attribute__((ext_vector_type(8)));   // 8 x bf16 bits
typedef float  f32x4 __attribute__((ext_vector_type(4)));

union F8 { frag8 f; uint2 u2[2]; unsigned u[4]; };

#define MFMA16(a,b,c) __builtin_amdgcn_mfma_f32_16x16x32_bf16((a),(b),(c),0,0,0)

__device__ __forceinline__ unsigned short f2bf(float f) {
  unsigned u = __builtin_bit_cast(unsigned, f);
  return (unsigned short)((u + 0x7fffu + ((u >> 16) & 1u)) >> 16);   // RTN-even
}
__device__ __forceinline__ float bf2f(unsigned short s) {
  unsigned u = ((unsigned)s) << 16;
  return __builtin_bit_cast(float, u);
}
// packed f32x2 -> bf16x2 (RNE), single HW instruction; lo -> low half
__device__ __forceinline__ unsigned pkbf(float lo, float hi) {
  unsigned r;
  asm("v_cvt_pk_bf16_f32 %0, %1, %2" : "=v"(r) : "v"(lo), "v"(hi));
  return r;
}

// ---------------------------------------------------------------------------
// Prep: fp32 -> bf16 for A (vis||trn), W_qkv, W_out.
// ---------------------------------------------------------------------------
__global__ __launch_bounds__(256) void k_prep(
    const float* __restrict__ vis, const float* __restrict__ trn,
    const float* __restrict__ Wqkv, const float* __restrict__ Wout,
    unsigned short* __restrict__ Abf, unsigned short* __restrict__ Wqb,
    unsigned short* __restrict__ Wob)
{
  size_t i8 = ((size_t)blockIdx.x * 256 + threadIdx.x) * 8;
  const float* src;
  unsigned short* dst;
  if (i8 < 8388608) {
    src = (i8 < 4194304) ? vis + i8 : trn + (i8 - 4194304);
    dst = Abf + i8;
  } else if (i8 < 11534336) {
    size_t o = i8 - 8388608;  src = Wqkv + o; dst = Wqb + o;
  } else {
    size_t o = i8 - 11534336; src = Wout + o; dst = Wob + o;
  }
  float4 u = *(const float4*)src;
  float4 v = *(const float4*)(src + 4);
  uint4 w;
  w.x = pkbf(u.x, u.y); w.y = pkbf(u.z, u.w);
  w.z = pkbf(v.x, v.y); w.w = pkbf(v.z, v.w);
  *(uint4*)dst = w;
}

// ---------------------------------------------------------------------------
// GEMM1 (bf16 in): qkv = Abf @ Wqb.  128x128 tile, BK=32, global_load_lds A.
// ---------------------------------------------------------------------------
__global__ __launch_bounds__(256) void k_gemm_qkv_b(
    const unsigned short* __restrict__ Abf, const unsigned short* __restrict__ Wqb,
    unsigned short* __restrict__ qkv)
{
  __shared__ unsigned short As_[128 * 32];  // linear [row][32]
  __shared__ unsigned short Bs[128 * 40];   // [n][k] pad->40
  const int tid  = threadIdx.x;
  const int lane = tid & 63, wv = tid >> 6;
  const int lm = lane & 15, lg = lane >> 4;
  const int nt = blockIdx.x, mt = blockIdx.y;
  const int wr = (wv >> 1) * 64, wc = (wv & 1) * 64;

  f32x4 acc[4][4] = {};

  const unsigned short* agp =
      Abf + (size_t)(mt * 128 + wv * 32 + (lane >> 2)) * 1024 + (lane & 3) * 8;
  const int bn = (tid & 63) * 2, bk = (tid >> 6) * 8;

  for (int kt = 0; kt < 32; ++kt) {
    __syncthreads();
    {
      __builtin_amdgcn_global_load_lds(
          (const __attribute__((address_space(1))) void*)(agp + kt * 32),
          (__attribute__((address_space(3))) void*)&As_[wv * 1024], 16, 0, 0);
      __builtin_amdgcn_global_load_lds(
          (const __attribute__((address_space(1))) void*)(agp + 16 * 1024 + kt * 32),
          (__attribute__((address_space(3))) void*)&As_[wv * 1024 + 512], 16, 0, 0);
    }
    {
      const unsigned short* bp = Wqb + (size_t)(kt * 32 + bk) * 3072 + nt * 128 + bn;
      frag8 q0, q1;
#pragma unroll
      for (int i = 0; i < 8; ++i) {
        ushort2 t = *(const ushort2*)(bp + (size_t)i * 3072);
        q0[i] = (short)t.x; q1[i] = (short)t.y;
      }
      *(frag8*)&Bs[(bn)     * 40 + bk] = q0;
      *(frag8*)&Bs[(bn + 1) * 40 + bk] = q1;
    }
    __syncthreads();
    frag8 af[4], bfr[4];
#pragma unroll
    for (int mi = 0; mi < 4; ++mi)
      af[mi] = *(const frag8*)&As_[(wr + mi * 16 + lm) * 32 + lg * 8];
#pragma unroll
    for (int ni = 0; ni < 4; ++ni)
      bfr[ni] = *(const frag8*)&Bs[(wc + ni * 16 + lm) * 40 + lg * 8];
#pragma unroll
    for (int mi = 0; mi < 4; ++mi)
#pragma unroll
      for (int ni = 0; ni < 4; ++ni)
        acc[mi][ni] = MFMA16(af[mi], bfr[ni], acc[mi][ni]);
  }

#pragma unroll
  for (int mi = 0; mi < 4; ++mi)
#pragma unroll
    for (int ni = 0; ni < 4; ++ni)
#pragma unroll
      for (int r = 0; r < 4; ++r) {
        int row = mt * 128 + wr + mi * 16 + lg * 4 + r;
        int col = nt * 128 + wc + ni * 16 + lm;
        qkv[(size_t)row * 3072 + col] = f2bf(acc[mi][ni][r]);
      }
}

// ---------------------------------------------------------------------------
// V transpose: Vt[src][h][d=64][s=2048] bf16.
// ---------------------------------------------------------------------------
__global__ __launch_bounds__(256) void k_vt(
    const unsigned short* __restrict__ qkv, unsigned short* __restrict__ Vt)
{
  __shared__ unsigned short L[64 * 72];
  const int tid = threadIdx.x;
  const int sblk = blockIdx.x;              // 0..31
  const int by = blockIdx.y;                // src*16 + h
  const int src = by >> 4, h = by & 15;
  {
    int sl = tid >> 2, dc = tid & 3;
    const unsigned short* gp =
        qkv + (size_t)(src * 2048 + sblk * 64 + sl) * 3072 + 2048 + h * 64 + dc * 16;
    *(frag8*)&L[sl * 72 + dc * 16]     = *(const frag8*)gp;
    *(frag8*)&L[sl * 72 + dc * 16 + 8] = *(const frag8*)(gp + 8);
  }
  __syncthreads();
  int d = tid >> 2, sc = tid & 3;
  unsigned wbuf[8];
#pragma unroll
  for (int j = 0; j < 8; ++j) {
    unsigned lo = L[(sc * 16 + 2 * j)     * 72 + d];
    unsigned hi = L[(sc * 16 + 2 * j + 1) * 72 + d];
    wbuf[j] = lo | (hi << 16);
  }
  unsigned short* op =
      Vt + ((size_t)(src * 16 + h) * 64 + d) * 2048 + sblk * 64 + sc * 16;
  *(uint4*)op       = *(uint4*)&wbuf[0];
  *(uint4*)(op + 8) = *(uint4*)&wbuf[4];
}

// ---------------------------------------------------------------------------
// Attention, split-KV x2 (blockIdx.z = half). Swapped QK^T, fixed-max
// softmax (P = 2^S), P in registers; row sums accumulated on the MFMA pipe
// via an all-ones B fragment (no VALU adds, no epilogue shuffles); shared
// zero C-in for QK accumulators (no per-iter re-zeroing).
// ---------------------------------------------------------------------------
__global__ __launch_bounds__(256) void k_attn(
    const unsigned short* __restrict__ qkv, const unsigned short* __restrict__ Vt,
    unsigned short* __restrict__ Opart, float* __restrict__ lpart)
{
  __shared__ unsigned short Ks[2][32 * 72];
  __shared__ unsigned short Vs[2][8 * 272];
  const int tid  = threadIdx.x;
  const int lane = tid & 63, wv = tid >> 6;
  const int lm = lane & 15, lg = lane >> 4;
  const int qt = blockIdx.x, comb = blockIdx.y;
  const int dir = comb >> 5, bb = (comb >> 4) & 1, h = comb & 15;
  const int half = blockIdx.z;
  const int NT = 32, kt0 = half * 32;
  const int qbase  = (dir ? 4096 : 0) + bb * 2048;
  const int kvbase = (dir ? 0 : 4096) + bb * 2048;
  const int qcol = h * 64, kcol = 1024 + h * 64;

  // constants: zero C-in quad, all-ones bf16 B-fragment (1.0 = 0x3F80)
  const f32x4 czero = {0.0f, 0.0f, 0.0f, 0.0f};
  F8 ones_;
  ones_.u[0] = 0x3F803F80u; ones_.u[1] = 0x3F803F80u;
  ones_.u[2] = 0x3F803F80u; ones_.u[3] = 0x3F803F80u;
  const frag8 onesf = ones_.f;

  // Q fragments, prescaled by 0.125*log2(e) (log2-domain scores).
  const float QS = 0.125f * 1.44269504f;
  frag8 qf[2][2];
#pragma unroll
  for (int mi = 0; mi < 2; ++mi)
#pragma unroll
    for (int kb = 0; kb < 2; ++kb) {
      frag8 t = *(const frag8*)&qkv[
          (size_t)(qbase + qt * 128 + wv * 32 + mi * 16 + lm) * 3072 +
          qcol + kb * 32 + lg * 8];
#pragma unroll
      for (int j = 0; j < 8; ++j)
        t[j] = (short)f2bf(bf2f((unsigned short)t[j]) * QS);
      qf[mi][kb] = t;
    }

  f32x4 acc[2][4] = {};
  f32x4 sacc[2] = {};                        // MFMA-accumulated P row-sums

  // staging: K row skv / 8 cols at sd ; V^T row d = tid>>2, kv chunk c = tid&3
  const int skv = tid >> 3, sd = (tid & 7) * 8;
  const int vd = tid >> 2, vc = tid & 3;
  const unsigned short* __restrict__ kp =
      qkv + (size_t)(kvbase + skv) * 3072 + kcol + sd;
  const unsigned short* __restrict__ vtp =
      Vt + ((size_t)((kvbase >> 11) * 16 + h) * 64 + vd) * 2048 + vc * 8;

  frag8 Rk, Rv;

#define LOAD_R(kt_) do {                                                   \
    Rk = *(const frag8*)(kp + (size_t)(kt_) * (32 * 3072));                \
    Rv = *(const frag8*)(vtp + (size_t)(kt_) * 32);                        \
  } while (0)

#define WRITE_R(s_) do {                                                   \
    *(frag8*)&Ks[s_][skv * 72 + sd] = Rk;                                  \
    F8 tv_; tv_.f = Rv;                                                    \
    *(uint2*)&Vs[s_][(2 * vc) * 272 + vd * 4]     = tv_.u2[0];             \
    *(uint2*)&Vs[s_][(2 * vc + 1) * 272 + vd * 4] = tv_.u2[1];             \
  } while (0)

  LOAD_R(kt0);
  WRITE_R(0);
  LOAD_R(kt0 + 1);

  for (int i = 0; i < NT; ++i) {
    __syncthreads();
    if (i < NT - 1) WRITE_R((i + 1) & 1);    // R holds tile i+1
    if (i < NT - 2) LOAD_R(kt0 + i + 2);     // in flight during compute
    const int s = i & 1;

    // S^T = K Q^T.  q = lm, kv = 16t + 4lg + r.  First MFMA uses shared
    // zero C-in (no per-iter accumulator re-zeroing).
    frag8 kf[2][2];
#pragma unroll
    for (int t = 0; t < 2; ++t)
#pragma unroll
      for (int kb = 0; kb < 2; ++kb)
        kf[t][kb] = *(const frag8*)&Ks[s][(t * 16 + lm) * 72 + kb * 32 + lg * 8];
    f32x4 st[2][2];
#pragma unroll
    for (int mi = 0; mi < 2; ++mi)
#pragma unroll
      for (int t = 0; t < 2; ++t) {
        st[mi][t] = MFMA16(kf[t][0], qf[mi][0], czero);
        st[mi][t] = MFMA16(kf[t][1], qf[mi][1], st[mi][t]);
      }

    // fixed-max softmax: P = 2^S, branch-free; pack to PV A-frags
    // (kv-bijection f(lg,j): j<4 -> 4lg+j ; j>=4 -> 16+4lg+(j-4))
    frag8 pa[2];
#pragma unroll
    for (int mi = 0; mi < 2; ++mi) {
      f32x4 a = st[mi][0], b = st[mi][1];
      float p[8];
#pragma unroll
      for (int r = 0; r < 4; ++r) p[r]     = exp2f(a[r]);
#pragma unroll
      for (int r = 0; r < 4; ++r) p[4 + r] = exp2f(b[r]);
      F8 pk_;
      pk_.u[0] = pkbf(p[0], p[1]); pk_.u[1] = pkbf(p[2], p[3]);
      pk_.u[2] = pkbf(p[4], p[5]); pk_.u[3] = pkbf(p[6], p[7]);
      pa[mi] = pk_.f;
      // row sums on the MFMA pipe: D[q][*] += sum_kv P[q][kv]
      sacc[mi] = MFMA16(pa[mi], onesf, sacc[mi]);
    }

    // O += P V
    frag8 vb[4];
#pragma unroll
    for (int di = 0; di < 4; ++di) {
      F8 t;
      t.u2[0] = *(const uint2*)&Vs[s][lg * 272 + (di * 16 + lm) * 4];
      t.u2[1] = *(const uint2*)&Vs[s][(4 + lg) * 272 + (di * 16 + lm) * 4];
      vb[di] = t.f;
    }
#pragma unroll
    for (int mi = 0; mi < 2; ++mi)
#pragma unroll
      for (int di = 0; di < 4; ++di)
        acc[mi][di] = MFMA16(pa[mi], vb[di], acc[mi][di]);
  }

#undef LOAD_R
#undef WRITE_R

  // bf16 unnormalized partials + per-HEAD fp32 row sums (each lane holds its
  // own rows' sums in sacc — column-independent, so lm==0 lanes store them).
#pragma unroll
  for (int mi = 0; mi < 2; ++mi) {
    int rowb = bb * 2048 + qt * 128 + wv * 32 + mi * 16;
    if (lm == 0) {
#pragma unroll
      for (int r = 0; r < 4; ++r)
        lpart[(size_t)(half * 2 + dir) * 65536 + h * 4096 + rowb + lg * 4 + r] =
            sacc[mi][r];
    }
#pragma unroll
    for (int r = 0; r < 4; ++r) {
      int row = rowb + lg * 4 + r;
#pragma unroll
      for (int di = 0; di < 4; ++di) {
        int col = h * 64 + di * 16 + lm;
        Opart[((size_t)(half * 2 + dir) * 4096 + row) * 1024 + col] =
            f2bf(acc[mi][di][r]);
      }
    }
  }
}

// ---------------------------------------------------------------------------
// Combine: a = (O0 + O1) / (l0 + l1), bf16. Op bf16 [half][dir][4096][1024];
// lp fp32 [half][dir][h][4096] (h = col/64).
// ---------------------------------------------------------------------------
__global__ __launch_bounds__(256) void k_combine(
    const unsigned short* __restrict__ Op, const float* __restrict__ lp,
    unsigned short* __restrict__ a0, unsigned short* __restrict__ a1)
{
  int g   = blockIdx.x * 256 + threadIdx.x;
  int col = (g & 255) << 2;
  int row = (g >> 8) & 4095;
  int dir = g >> 20;
  int h   = col >> 6;                       // 4 cols never straddle a head
  float l = lp[(size_t)dir * 65536 + h * 4096 + row] +
            lp[(size_t)(2 + dir) * 65536 + h * 4096 + row];
  float inv = 1.0f / l;
  const unsigned short* pu = &Op[((size_t)dir * 4096 + row) * 1024 + col];
  const unsigned short* pv = &Op[((size_t)(2 + dir) * 4096 + row) * 1024 + col];
  uint2 w;
  w.x = pkbf((bf2f(pu[0]) + bf2f(pv[0])) * inv, (bf2f(pu[1]) + bf2f(pv[1])) * inv);
  w.y = pkbf((bf2f(pu[2]) + bf2f(pv[2])) * inv, (bf2f(pu[3]) + bf2f(pv[3])) * inv);
  unsigned short* dst = dir ? a1 : a0;
  *(uint2*)&dst[(size_t)row * 1024 + col] = w;
}

// ---------------------------------------------------------------------------
// GEMM2: out = (attn0 + attn1) @ Wob (bf16 weights).
// ---------------------------------------------------------------------------
__global__ __launch_bounds__(256) void k_gemm_out_b(
    const unsigned short* __restrict__ x0, const unsigned short* __restrict__ x1,
    const unsigned short* __restrict__ Wob, float* __restrict__ out)
{
  __shared__ unsigned short As[128 * 40];
  __shared__ unsigned short Bs[128 * 40];
  const int tid  = threadIdx.x;
  const int lane = tid & 63, wv = tid >> 6;
  const int lm = lane & 15, lg = lane >> 4;
  const int nt = blockIdx.x, mt = blockIdx.y;
  const int wr = (wv >> 1) * 64, wc = (wv & 1) * 64;

  f32x4 acc[4][4] = {};

  const int am = tid >> 1, akq = (tid & 1) * 16;
  const int arow = mt * 128 + am;
  const unsigned short* __restrict__ a0p = x0 + (size_t)arow * 1024;
  const unsigned short* __restrict__ a1p = x1 + (size_t)arow * 1024;
  const int bn = (tid & 63) * 2, bk = (tid >> 6) * 8;

  for (int kt = 0; kt < 32; ++kt) {
    __syncthreads();
    { // stage A = x0 + x1
      frag8 u0 = *(const frag8*)(a0p + kt * 32 + akq);
      frag8 u1 = *(const frag8*)(a0p + kt * 32 + akq + 8);
      frag8 w0 = *(const frag8*)(a1p + kt * 32 + akq);
      frag8 w1 = *(const frag8*)(a1p + kt * 32 + akq + 8);
      frag8 p0, p1;
#pragma unroll
      for (int j = 0; j < 8; ++j) {
        p0[j] = (short)f2bf(bf2f((unsigned short)u0[j]) + bf2f((unsigned short)w0[j]));
        p1[j] = (short)f2bf(bf2f((unsigned short)u1[j]) + bf2f((unsigned short)w1[j]));
      }
      *(frag8*)&As[am * 40 + akq]     = p0;
      *(frag8*)&As[am * 40 + akq + 8] = p1;
    }
    { // stage B transposed (bf16)
      const unsigned short* bp = Wob + (size_t)(kt * 32 + bk) * 1024 + nt * 128 + bn;
      frag8 q0, q1;
#pragma unroll
      for (int i = 0; i < 8; ++i) {
        ushort2 t = *(const ushort2*)(bp + (size_t)i * 1024);
        q0[i] = (short)t.x; q1[i] = (short)t.y;
      }
      *(frag8*)&Bs[(bn)     * 40 + bk] = q0;
      *(frag8*)&Bs[(bn + 1) * 40 + bk] = q1;
    }
    __syncthreads();
    frag8 af[4], bfr[4];
#pragma unroll
    for (int mi = 0; mi < 4; ++mi)
      af[mi] = *(const frag8*)&As[(wr + mi * 16 + lm) * 40 + lg * 8];
#pragma unroll
    for (int ni = 0; ni < 4; ++ni)
      bfr[ni] = *(const frag8*)&Bs[(wc + ni * 16 + lm) * 40 + lg * 8];
#pragma unroll
    for (int mi = 0; mi < 4; ++mi)
#pragma unroll
      for (int ni = 0; ni < 4; ++ni)
        acc[mi][ni] = MFMA16(af[mi], bfr[ni], acc[mi][ni]);
  }

#pragma unroll
  for (int mi = 0; mi < 4; ++mi)
#pragma unroll
    for (int ni = 0; ni < 4; ++ni)
#pragma unroll
      for (int r = 0; r < 4; ++r) {
        int row = mt * 128 + wr + mi * 16 + lg * 4 + r;
        int col = nt * 128 + wc + ni * 16 + lm;
        out[(size_t)row * 1024 + col] = acc[mi][ni][r];
      }
}

// ---------------------------------------------------------------------------
extern "C" void kernel_launch(void* const* d_in, const int* in_sizes, int n_in,
                              void* d_out, int out_size, void* d_ws, size_t ws_size,
                              hipStream_t stream)
{
  const float* vis  = (const float*)d_in[0];
  const float* trn  = (const float*)d_in[1];
  const float* Wqkv = (const float*)d_in[2];
  const float* Wout = (const float*)d_in[3];
  float* out = (float*)d_out;

  char* base = (char*)d_ws;
  unsigned short* qkv = (unsigned short*)base;                  // 50331648 B
  unsigned short* a0  = (unsigned short*)(base + 50331648UL);   //  8388608 B
  unsigned short* a1  = a0 + 4194304;                           //  8388608 B
  unsigned short* Vt  = (unsigned short*)(base + 67108864UL);   // 16777216 B
  unsigned short* Wob = (unsigned short*)(base + 83886080UL);   //  2097152 B
  float*          lp  = (float*)(base + 85983232UL);            //  1048576 B
  // X region (87031808..): Abf(16M)+Wqb(6M) alias Op(32M) — disjoint lifetimes
  unsigned short* Abf = (unsigned short*)(base + 87031808UL);
  unsigned short* Wqb = Abf + 8388608;
  unsigned short* Op  = (unsigned short*)(base + 87031808UL);
  // need = 87031808 + 33554432 = 120586240 B

  k_prep     <<<6144, 256, 0, stream>>>(vis, trn, Wqkv, Wout, Abf, Wqb, Wob);
  k_gemm_qkv_b<<<dim3(24, 64), 256, 0, stream>>>(Abf, Wqb, qkv);
  k_vt       <<<dim3(32, 64), 256, 0, stream>>>(qkv, Vt);
  k_attn     <<<dim3(16, 64, 2), 256, 0, stream>>>(qkv, Vt, Op, lp);
  k_combine  <<<8192, 256, 0, stream>>>(Op, lp, a0, a1);
  k_gemm_out_b<<<dim3(8, 32), 256, 0, stream>>>(a0, a1, Wob, out);
}

// Round 14
// 243.722 us; speedup vs baseline: 1.1113x; 1.1113x over previous
//
#include <hip/hip_runtime.h>

// ---------------------------------------------------------------------------
// CrossModalAttention: out = (attn(v_q, t_k, t_v) + attn(t_q, v_k, v_v)) @ W_out
// Pipeline: k_prep (A fp32->bf16) + k_wt (W fp32->bf16 TRANSPOSED, so both
// GEMMs stage B via global_load_lds) -> k_gemm_qkv_b -> k_vt -> k_attn
// splitKV x2 (fixed-max softmax with RAW v_exp_f32, P in regs, bf16
// partials) -> k_combine -> k_gemm_out_b.
// MFMA bf16/fp32-acc; A/B fragments use the SAME k-bijection (HW schedule
// cancels). C/D: col=lane&15, row=4*(lane>>4)+reg.
// ---------------------------------------------------------------------------

typedef short  frag8 __attribute__((ext_vector_type(8)));   // 8 x bf16 bits
typedef float  f32x4 __attribute__((ext_vector_type(4)));

union F8 { frag8 f; uint2 u2[2]; unsigned u[4]; };

#define MFMA16(a,b,c) __builtin_amdgcn_mfma_f32_16x16x32_bf16((a),(b),(c),0,0,0)

__device__ __forceinline__ unsigned short f2bf(float f) {
  unsigned u = __builtin_bit_cast(unsigned, f);
  return (unsigned short)((u + 0x7fffu + ((u >> 16) & 1u)) >> 16);   // RTN-even
}
__device__ __forceinline__ float bf2f(unsigned short s) {
  unsigned u = ((unsigned)s) << 16;
  return __builtin_bit_cast(float, u);
}
// packed f32x2 -> bf16x2 (RNE), single HW instruction; lo -> low half
__device__ __forceinline__ unsigned pkbf(float lo, float hi) {
  unsigned r;
  asm("v_cvt_pk_bf16_f32 %0, %1, %2" : "=v"(r) : "v"(lo), "v"(hi));
  return r;
}
// raw 2^x — 1 instruction; our args are bounded (|x| << 126) so the libm
// denormal-range guard (the ~5-inst ocml expansion) is unnecessary.
__device__ __forceinline__ float fexp2(float x) {
  float r;
  asm("v_exp_f32 %0, %1" : "=v"(r) : "v"(x));
  return r;
}

// ---------------------------------------------------------------------------
// Prep A: fp32 (vis||trn) -> bf16 Abf. 8388608 elems / 8 = 4096 blocks.
// ---------------------------------------------------------------------------
__global__ __launch_bounds__(256) void k_prep(
    const float* __restrict__ vis, const float* __restrict__ trn,
    unsigned short* __restrict__ Abf)
{
  size_t i8 = ((size_t)blockIdx.x * 256 + threadIdx.x) * 8;
  const float* src = (i8 < 4194304) ? vis + i8 : trn + (i8 - 4194304);
  float4 u = *(const float4*)src;
  float4 v = *(const float4*)(src + 4);
  uint4 w;
  w.x = pkbf(u.x, u.y); w.y = pkbf(u.z, u.w);
  w.z = pkbf(v.x, v.y); w.w = pkbf(v.z, v.w);
  *(uint4*)(Abf + i8) = w;
}

// ---------------------------------------------------------------------------
// Weight transpose+convert: W fp32 [1024][N] -> Wt bf16 [N][1024].
// 64x64 tiles through LDS.
// ---------------------------------------------------------------------------
__global__ __launch_bounds__(256) void k_wt(
    const float* __restrict__ W, unsigned short* __restrict__ Wt, int N)
{
  __shared__ unsigned short L[64 * 72];
  const int tid = threadIdx.x;
  const int n0 = blockIdx.x * 64, k0 = blockIdx.y * 64;
  {
    int kr = tid >> 2, c4 = (tid & 3) * 16;
    const float* gp = W + (size_t)(k0 + kr) * N + n0 + c4;
    float4 u0 = *(const float4*)gp,       u1 = *(const float4*)(gp + 4);
    float4 u2 = *(const float4*)(gp + 8), u3 = *(const float4*)(gp + 12);
    unsigned* lw = (unsigned*)&L[kr * 72 + c4];
    lw[0] = pkbf(u0.x, u0.y); lw[1] = pkbf(u0.z, u0.w);
    lw[2] = pkbf(u1.x, u1.y); lw[3] = pkbf(u1.z, u1.w);
    lw[4] = pkbf(u2.x, u2.y); lw[5] = pkbf(u2.z, u2.w);
    lw[6] = pkbf(u3.x, u3.y); lw[7] = pkbf(u3.z, u3.w);
  }
  __syncthreads();
  int nr = tid >> 2, kc = (tid & 3) * 16;
  unsigned wb[8];
#pragma unroll
  for (int j = 0; j < 8; ++j) {
    unsigned lo = L[(kc + 2 * j)     * 72 + nr];
    unsigned hi = L[(kc + 2 * j + 1) * 72 + nr];
    wb[j] = lo | (hi << 16);
  }
  unsigned short* op = Wt + (size_t)(n0 + nr) * 1024 + k0 + kc;
  *(uint4*)op       = *(uint4*)&wb[0];
  *(uint4*)(op + 8) = *(uint4*)&wb[4];
}

// ---------------------------------------------------------------------------
// GEMM1: qkv = Abf @ WqbT^T. A [8192x1024], B^T [3072x1024] bf16.
// 128x128 tile, BK=32; BOTH operands staged via global_load_lds (16B,
// linear [128][32] LDS).
// ---------------------------------------------------------------------------
__global__ __launch_bounds__(256) void k_gemm_qkv_b(
    const unsigned short* __restrict__ Abf, const unsigned short* __restrict__ WqbT,
    unsigned short* __restrict__ qkv)
{
  __shared__ unsigned short As_[128 * 32];
  __shared__ unsigned short Bs_[128 * 32];
  const int tid  = threadIdx.x;
  const int lane = tid & 63, wv = tid >> 6;
  const int lm = lane & 15, lg = lane >> 4;
  const int nt = blockIdx.x, mt = blockIdx.y;
  const int wr = (wv >> 1) * 64, wc = (wv & 1) * 64;

  f32x4 acc[4][4] = {};

  const unsigned short* agp =
      Abf + (size_t)(mt * 128 + wv * 32 + (lane >> 2)) * 1024 + (lane & 3) * 8;
  const unsigned short* bgp =
      WqbT + (size_t)(nt * 128 + wv * 32 + (lane >> 2)) * 1024 + (lane & 3) * 8;

  for (int kt = 0; kt < 32; ++kt) {
    __syncthreads();
    __builtin_amdgcn_global_load_lds(
        (const __attribute__((address_space(1))) void*)(agp + kt * 32),
        (__attribute__((address_space(3))) void*)&As_[wv * 1024], 16, 0, 0);
    __builtin_amdgcn_global_load_lds(
        (const __attribute__((address_space(1))) void*)(agp + 16 * 1024 + kt * 32),
        (__attribute__((address_space(3))) void*)&As_[wv * 1024 + 512], 16, 0, 0);
    __builtin_amdgcn_global_load_lds(
        (const __attribute__((address_space(1))) void*)(bgp + kt * 32),
        (__attribute__((address_space(3))) void*)&Bs_[wv * 1024], 16, 0, 0);
    __builtin_amdgcn_global_load_lds(
        (const __attribute__((address_space(1))) void*)(bgp + 16 * 1024 + kt * 32),
        (__attribute__((address_space(3))) void*)&Bs_[wv * 1024 + 512], 16, 0, 0);
    __syncthreads();
    frag8 af[4], bfr[4];
#pragma unroll
    for (int mi = 0; mi < 4; ++mi)
      af[mi] = *(const frag8*)&As_[(wr + mi * 16 + lm) * 32 + lg * 8];
#pragma unroll
    for (int ni = 0; ni < 4; ++ni)
      bfr[ni] = *(const frag8*)&Bs_[(wc + ni * 16 + lm) * 32 + lg * 8];
#pragma unroll
    for (int mi = 0; mi < 4; ++mi)
#pragma unroll
      for (int ni = 0; ni < 4; ++ni)
        acc[mi][ni] = MFMA16(af[mi], bfr[ni], acc[mi][ni]);
  }

#pragma unroll
  for (int mi = 0; mi < 4; ++mi)
#pragma unroll
    for (int ni = 0; ni < 4; ++ni)
#pragma unroll
      for (int r = 0; r < 4; ++r) {
        int row = mt * 128 + wr + mi * 16 + lg * 4 + r;
        int col = nt * 128 + wc + ni * 16 + lm;
        qkv[(size_t)row * 3072 + col] = f2bf(acc[mi][ni][r]);
      }
}

// ---------------------------------------------------------------------------
// V transpose: Vt[src][h][d=64][s=2048] bf16.
// ---------------------------------------------------------------------------
__global__ __launch_bounds__(256) void k_vt(
    const unsigned short* __restrict__ qkv, unsigned short* __restrict__ Vt)
{
  __shared__ unsigned short L[64 * 72];
  const int tid = threadIdx.x;
  const int sblk = blockIdx.x;              // 0..31
  const int by = blockIdx.y;                // src*16 + h
  const int src = by >> 4, h = by & 15;
  {
    int sl = tid >> 2, dc = tid & 3;
    const unsigned short* gp =
        qkv + (size_t)(src * 2048 + sblk * 64 + sl) * 3072 + 2048 + h * 64 + dc * 16;
    *(frag8*)&L[sl * 72 + dc * 16]     = *(const frag8*)gp;
    *(frag8*)&L[sl * 72 + dc * 16 + 8] = *(const frag8*)(gp + 8);
  }
  __syncthreads();
  int d = tid >> 2, sc = tid & 3;
  unsigned wbuf[8];
#pragma unroll
  for (int j = 0; j < 8; ++j) {
    unsigned lo = L[(sc * 16 + 2 * j)     * 72 + d];
    unsigned hi = L[(sc * 16 + 2 * j + 1) * 72 + d];
    wbuf[j] = lo | (hi << 16);
  }
  unsigned short* op =
      Vt + ((size_t)(src * 16 + h) * 64 + d) * 2048 + sblk * 64 + sc * 16;
  *(uint4*)op       = *(uint4*)&wbuf[0];
  *(uint4*)(op + 8) = *(uint4*)&wbuf[4];
}

// ---------------------------------------------------------------------------
// Attention, split-KV x2 (blockIdx.z = half). Swapped QK^T, fixed-max
// softmax (P = 2^S via raw v_exp_f32), P in registers, bf16 partials.
// ---------------------------------------------------------------------------
__global__ __launch_bounds__(256) void k_attn(
    const unsigned short* __restrict__ qkv, const unsigned short* __restrict__ Vt,
    unsigned short* __restrict__ Opart, float* __restrict__ lpart)
{
  __shared__ unsigned short Ks[2][32 * 72];
  __shared__ unsigned short Vs[2][8 * 272];
  const int tid  = threadIdx.x;
  const int lane = tid & 63, wv = tid >> 6;
  const int lm = lane & 15, lg = lane >> 4;
  const int qt = blockIdx.x, comb = blockIdx.y;
  const int dir = comb >> 5, bb = (comb >> 4) & 1, h = comb & 15;
  const int half = blockIdx.z;
  const int NT = 32, kt0 = half * 32;
  const int qbase  = (dir ? 4096 : 0) + bb * 2048;
  const int kvbase = (dir ? 0 : 4096) + bb * 2048;
  const int qcol = h * 64, kcol = 1024 + h * 64;

  // Q fragments, prescaled by 0.125*log2(e) (log2-domain scores).
  const float QS = 0.125f * 1.44269504f;
  frag8 qf[2][2];
#pragma unroll
  for (int mi = 0; mi < 2; ++mi)
#pragma unroll
    for (int kb = 0; kb < 2; ++kb) {
      frag8 t = *(const frag8*)&qkv[
          (size_t)(qbase + qt * 128 + wv * 32 + mi * 16 + lm) * 3072 +
          qcol + kb * 32 + lg * 8];
#pragma unroll
      for (int j = 0; j < 8; ++j)
        t[j] = (short)f2bf(bf2f((unsigned short)t[j]) * QS);
      qf[mi][kb] = t;
    }

  f32x4 acc[2][4] = {};
  float lr[2] = {0.0f, 0.0f};

  // staging: K row skv / 8 cols at sd ; V^T row d = tid>>2, kv chunk c = tid&3
  const int skv = tid >> 3, sd = (tid & 7) * 8;
  const int vd = tid >> 2, vc = tid & 3;
  const unsigned short* __restrict__ kp =
      qkv + (size_t)(kvbase + skv) * 3072 + kcol + sd;
  const unsigned short* __restrict__ vtp =
      Vt + ((size_t)((kvbase >> 11) * 16 + h) * 64 + vd) * 2048 + vc * 8;

  frag8 Rk, Rv;

#define LOAD_R(kt_) do {                                                   \
    Rk = *(const frag8*)(kp + (size_t)(kt_) * (32 * 3072));                \
    Rv = *(const frag8*)(vtp + (size_t)(kt_) * 32);                        \
  } while (0)

#define WRITE_R(s_) do {                                                   \
    *(frag8*)&Ks[s_][skv * 72 + sd] = Rk;                                  \
    F8 tv_; tv_.f = Rv;                                                    \
    *(uint2*)&Vs[s_][(2 * vc) * 272 + vd * 4]     = tv_.u2[0];             \
    *(uint2*)&Vs[s_][(2 * vc + 1) * 272 + vd * 4] = tv_.u2[1];             \
  } while (0)

  LOAD_R(kt0);
  WRITE_R(0);
  LOAD_R(kt0 + 1);

  for (int i = 0; i < NT; ++i) {
    __syncthreads();
    if (i < NT - 1) WRITE_R((i + 1) & 1);    // R holds tile i+1
    if (i < NT - 2) LOAD_R(kt0 + i + 2);     // in flight during compute
    const int s = i & 1;

    // S^T = K Q^T.  q = lm, kv = 16t + 4lg + r.
    frag8 kf[2][2];
#pragma unroll
    for (int t = 0; t < 2; ++t)
#pragma unroll
      for (int kb = 0; kb < 2; ++kb)
        kf[t][kb] = *(const frag8*)&Ks[s][(t * 16 + lm) * 72 + kb * 32 + lg * 8];
    f32x4 st[2][2] = {};
#pragma unroll
    for (int mi = 0; mi < 2; ++mi)
#pragma unroll
      for (int t = 0; t < 2; ++t)
#pragma unroll
        for (int kb = 0; kb < 2; ++kb)
          st[mi][t] = MFMA16(kf[t][kb], qf[mi][kb], st[mi][t]);

    // fixed-max softmax: P = 2^S (1-inst exp), branch-free; pack to PV
    // A-frags (kv-bijection f(lg,j): j<4 -> 4lg+j ; j>=4 -> 16+4lg+(j-4))
    frag8 pa[2];
#pragma unroll
    for (int mi = 0; mi < 2; ++mi) {
      f32x4 a = st[mi][0], b = st[mi][1];
      float p[8];
#pragma unroll
      for (int r = 0; r < 4; ++r) p[r]     = fexp2(a[r]);
#pragma unroll
      for (int r = 0; r < 4; ++r) p[4 + r] = fexp2(b[r]);
      lr[mi] += ((p[0] + p[1]) + (p[2] + p[3])) +
                ((p[4] + p[5]) + (p[6] + p[7]));
      F8 pk_;
      pk_.u[0] = pkbf(p[0], p[1]); pk_.u[1] = pkbf(p[2], p[3]);
      pk_.u[2] = pkbf(p[4], p[5]); pk_.u[3] = pkbf(p[6], p[7]);
      pa[mi] = pk_.f;
    }

    // O += P V
    frag8 vb[4];
#pragma unroll
    for (int di = 0; di < 4; ++di) {
      F8 t;
      t.u2[0] = *(const uint2*)&Vs[s][lg * 272 + (di * 16 + lm) * 4];
      t.u2[1] = *(const uint2*)&Vs[s][(4 + lg) * 272 + (di * 16 + lm) * 4];
      vb[di] = t.f;
    }
#pragma unroll
    for (int mi = 0; mi < 2; ++mi)
#pragma unroll
      for (int di = 0; di < 4; ++di)
        acc[mi][di] = MFMA16(pa[mi], vb[di], acc[mi][di]);
  }

#undef LOAD_R
#undef WRITE_R

  // bf16 unnormalized partials + per-HEAD fp32 row sums
#pragma unroll
  for (int mi = 0; mi < 2; ++mi) {
    float l = lr[mi];
    l += __shfl_xor(l, 16);
    l += __shfl_xor(l, 32);
    int rowb = bb * 2048 + qt * 128 + wv * 32 + mi * 16;
    if (lane < 16)
      lpart[(size_t)(half * 2 + dir) * 65536 + h * 4096 + rowb + lane] = l;
#pragma unroll
    for (int r = 0; r < 4; ++r) {
      int row = rowb + lg * 4 + r;
#pragma unroll
      for (int di = 0; di < 4; ++di) {
        int col = h * 64 + di * 16 + lm;
        Opart[((size_t)(half * 2 + dir) * 4096 + row) * 1024 + col] =
            f2bf(acc[mi][di][r]);
      }
    }
  }
}

// ---------------------------------------------------------------------------
// Combine: a = (O0 + O1) / (l0 + l1), bf16. Op bf16 [half][dir][4096][1024];
// lp fp32 [half][dir][h][4096] (h = col/64).
// ---------------------------------------------------------------------------
__global__ __launch_bounds__(256) void k_combine(
    const unsigned short* __restrict__ Op, const float* __restrict__ lp,
    unsigned short* __restrict__ a0, unsigned short* __restrict__ a1)
{
  int g   = blockIdx.x * 256 + threadIdx.x;
  int col = (g & 255) << 2;
  int row = (g >> 8) & 4095;
  int dir = g >> 20;
  int h   = col >> 6;                       // 4 cols never straddle a head
  float l = lp[(size_t)dir * 65536 + h * 4096 + row] +
            lp[(size_t)(2 + dir) * 65536 + h * 4096 + row];
  float inv = 1.0f / l;
  const unsigned short* pu = &Op[((size_t)dir * 4096 + row) * 1024 + col];
  const unsigned short* pv = &Op[((size_t)(2 + dir) * 4096 + row) * 1024 + col];
  uint2 w;
  w.x = pkbf((bf2f(pu[0]) + bf2f(pv[0])) * inv, (bf2f(pu[1]) + bf2f(pv[1])) * inv);
  w.y = pkbf((bf2f(pu[2]) + bf2f(pv[2])) * inv, (bf2f(pu[3]) + bf2f(pv[3])) * inv);
  unsigned short* dst = dir ? a1 : a0;
  *(uint2*)&dst[(size_t)row * 1024 + col] = w;
}

// ---------------------------------------------------------------------------
// GEMM2: out = (attn0 + attn1) @ WobT^T. A staged with add (VALU);
// B via global_load_lds from WobT [1024][1024].
// ---------------------------------------------------------------------------
__global__ __launch_bounds__(256) void k_gemm_out_b(
    const unsigned short* __restrict__ x0, const unsigned short* __restrict__ x1,
    const unsigned short* __restrict__ WobT, float* __restrict__ out)
{
  __shared__ unsigned short As[128 * 40];
  __shared__ unsigned short Bs_[128 * 32];
  const int tid  = threadIdx.x;
  const int lane = tid & 63, wv = tid >> 6;
  const int lm = lane & 15, lg = lane >> 4;
  const int nt = blockIdx.x, mt = blockIdx.y;
  const int wr = (wv >> 1) * 64, wc = (wv & 1) * 64;

  f32x4 acc[4][4] = {};

  const int am = tid >> 1, akq = (tid & 1) * 16;
  const int arow = mt * 128 + am;
  const unsigned short* __restrict__ a0p = x0 + (size_t)arow * 1024;
  const unsigned short* __restrict__ a1p = x1 + (size_t)arow * 1024;
  const unsigned short* bgp =
      WobT + (size_t)(nt * 128 + wv * 32 + (lane >> 2)) * 1024 + (lane & 3) * 8;

  for (int kt = 0; kt < 32; ++kt) {
    __syncthreads();
    __builtin_amdgcn_global_load_lds(
        (const __attribute__((address_space(1))) void*)(bgp + kt * 32),
        (__attribute__((address_space(3))) void*)&Bs_[wv * 1024], 16, 0, 0);
    __builtin_amdgcn_global_load_lds(
        (const __attribute__((address_space(1))) void*)(bgp + 16 * 1024 + kt * 32),
        (__attribute__((address_space(3))) void*)&Bs_[wv * 1024 + 512], 16, 0, 0);
    { // stage A = x0 + x1
      frag8 u0 = *(const frag8*)(a0p + kt * 32 + akq);
      frag8 u1 = *(const frag8*)(a0p + kt * 32 + akq + 8);
      frag8 w0 = *(const frag8*)(a1p + kt * 32 + akq);
      frag8 w1 = *(const frag8*)(a1p + kt * 32 + akq + 8);
      frag8 p0, p1;
#pragma unroll
      for (int j = 0; j < 8; ++j) {
        p0[j] = (short)f2bf(bf2f((unsigned short)u0[j]) + bf2f((unsigned short)w0[j]));
        p1[j] = (short)f2bf(bf2f((unsigned short)u1[j]) + bf2f((unsigned short)w1[j]));
      }
      *(frag8*)&As[am * 40 + akq]     = p0;
      *(frag8*)&As[am * 40 + akq + 8] = p1;
    }
    __syncthreads();
    frag8 af[4], bfr[4];
#pragma unroll
    for (int mi = 0; mi < 4; ++mi)
      af[mi] = *(const frag8*)&As[(wr + mi * 16 + lm) * 40 + lg * 8];
#pragma unroll
    for (int ni = 0; ni < 4; ++ni)
      bfr[ni] = *(const frag8*)&Bs_[(wc + ni * 16 + lm) * 32 + lg * 8];
#pragma unroll
    for (int mi = 0; mi < 4; ++mi)
#pragma unroll
      for (int ni = 0; ni < 4; ++ni)
        acc[mi][ni] = MFMA16(af[mi], bfr[ni], acc[mi][ni]);
  }

#pragma unroll
  for (int mi = 0; mi < 4; ++mi)
#pragma unroll
    for (int ni = 0; ni < 4; ++ni)
#pragma unroll
      for (int r = 0; r < 4; ++r) {
        int row = mt * 128 + wr + mi * 16 + lg * 4 + r;
        int col = nt * 128 + wc + ni * 16 + lm;
        out[(size_t)row * 1024 + col] = acc[mi][ni][r];
      }
}

// ---------------------------------------------------------------------------
extern "C" void kernel_launch(void* const* d_in, const int* in_sizes, int n_in,
                              void* d_out, int out_size, void* d_ws, size_t ws_size,
                              hipStream_t stream)
{
  const float* vis  = (const float*)d_in[0];
  const float* trn  = (const float*)d_in[1];
  const float* Wqkv = (const float*)d_in[2];
  const float* Wout = (const float*)d_in[3];
  float* out = (float*)d_out;

  char* base = (char*)d_ws;
  unsigned short* qkv  = (unsigned short*)base;                  // 50331648 B
  unsigned short* a0   = (unsigned short*)(base + 50331648UL);   //  8388608 B
  unsigned short* a1   = a0 + 4194304;                           //  8388608 B
  unsigned short* Vt   = (unsigned short*)(base + 67108864UL);   // 16777216 B
  unsigned short* WobT = (unsigned short*)(base + 83886080UL);   //  2097152 B
  float*          lp   = (float*)(base + 85983232UL);            //  1048576 B
  // X region (87031808..): Abf(16M)+WqbT(6M) alias Op(32M) — disjoint lives
  unsigned short* Abf  = (unsigned short*)(base + 87031808UL);
  unsigned short* WqbT = Abf + 8388608;
  unsigned short* Op   = (unsigned short*)(base + 87031808UL);
  // need = 87031808 + 33554432 = 120586240 B (confirmed fits, rounds 11-13)

  k_prep      <<<4096, 256, 0, stream>>>(vis, trn, Abf);
  k_wt        <<<dim3(48, 16), 256, 0, stream>>>(Wqkv, WqbT, 3072);
  k_wt        <<<dim3(16, 16), 256, 0, stream>>>(Wout, WobT, 1024);
  k_gemm_qkv_b<<<dim3(24, 64), 256, 0, stream>>>(Abf, WqbT, qkv);
  k_vt        <<<dim3(32, 64), 256, 0, stream>>>(qkv, Vt);
  k_attn      <<<dim3(16, 64, 2), 256, 0, stream>>>(qkv, Vt, Op, lp);
  k_combine   <<<8192, 256, 0, stream>>>(Op, lp, a0, a1);
  k_gemm_out_b<<<dim3(8, 32), 256, 0, stream>>>(a0, a1, WobT, out);
}